// Round 1
// baseline (101.944 us; speedup 1.0000x reference)
//
#include <hip/hip_runtime.h>
#include <hip/hip_bf16.h>
#include <math.h>

// Problem constants (match reference)
constexpr int KB_B  = 16;
constexpr int KB_H  = 12;
constexpr int KB_P  = 256;
constexpr int KB_D  = 64;
constexpr int KB_NF = 8;
constexpr int KB_NROWS = KB_B * KB_H * KB_P;      // 49152 rows per tensor

// ---------------------------------------------------------------------------
// Kernel A: sig_rowsum for q and k.
//   base = silu(x) @ base_weight.T           [row, d]
//   fk   = sum_f coef[d,f] * sin(grid[f]*x[d])
//   f    = fk*scale_sp + base*scale_base
//   out[row] = sum_d sigmoid(f[row,d])
// Block = 256 threads = 4 waves; each wave handles one row (64 dims).
// base_weight staged transposed+padded in LDS (conflict-free reads).
// ---------------------------------------------------------------------------
__global__ __launch_bounds__(256) void ka_sig_rowsum_kernel(
    const float* __restrict__ q, const float* __restrict__ k,
    const float* __restrict__ grid_v, const float* __restrict__ bw,
    const float* __restrict__ coef, const float* __restrict__ scale_base,
    const float* __restrict__ scale_sp,
    float* __restrict__ sq, float* __restrict__ sk)
{
    __shared__ float bwT[64 * 65];        // bwT[e*65 + d] = base_weight[d][e]
    __shared__ float silu_sh[4][64];

    const int tid  = threadIdx.x;
    const int lane = tid & 63;
    const int wv   = tid >> 6;

    // stage base_weight transposed (padded stride 65 to avoid bank conflicts)
    for (int n = tid; n < 64 * 64; n += 256) {
        int dd = n >> 6, e = n & 63;      // bw[dd][e]
        bwT[e * 65 + dd] = bw[n];
    }

    // per-lane coef[d=lane, 0..7] (32B aligned vector loads)
    const float4* c4 = reinterpret_cast<const float4*>(coef + lane * KB_NF);
    float4 ca = c4[0], cb = c4[1];
    float cf[KB_NF] = {ca.x, ca.y, ca.z, ca.w, cb.x, cb.y, cb.z, cb.w};
    float gr[KB_NF];
#pragma unroll
    for (int f = 0; f < KB_NF; ++f) gr[f] = grid_v[f];

    const int rowg = blockIdx.x * 4 + wv;               // 0 .. 2*NROWS-1
    const bool is_q = (rowg < KB_NROWS);
    const int row = is_q ? rowg : (rowg - KB_NROWS);
    const float* __restrict__ x = is_q ? q : k;
    float* __restrict__ outp = is_q ? sq : sk;

    const float xv = x[(size_t)row * KB_D + lane];
    const float sigx = 1.f / (1.f + __expf(-xv));
    silu_sh[wv][lane] = xv * sigx;
    __syncthreads();

    float base = 0.f;
#pragma unroll 8
    for (int e = 0; e < 64; ++e)
        base = fmaf(silu_sh[wv][e], bwT[e * 65 + lane], base);

    float fk = 0.f;
#pragma unroll
    for (int f = 0; f < KB_NF; ++f)
        fk = fmaf(cf[f], sinf(gr[f] * xv), fk);

    const int hp = row % (KB_H * KB_P);                 // scale tensors are [1,H,P,D]
    const int sidx = hp * KB_D + lane;
    const float fval = fk * scale_sp[sidx] + base * scale_base[sidx];
    float sg = 1.f / (1.f + __expf(-fval));

    // full-wave (64-lane) reduction
#pragma unroll
    for (int off = 32; off; off >>= 1) sg += __shfl_down(sg, off);
    if (lane == 0) outp[row] = sg;
}

// ---------------------------------------------------------------------------
// phi helpers (double): phi(z) = (e^z - 1)/z, phi'(z)
// ---------------------------------------------------------------------------
__device__ inline double ka_phi(double z) {
    if (fabs(z) < 1e-5)
        return 1.0 + z * (0.5 + z * (1.0 / 6.0 + z * (1.0 / 24.0)));
    return (exp(z) - 1.0) / z;
}
__device__ inline double ka_phip(double z) {
    if (fabs(z) < 1e-4)
        return 0.5 + z * (1.0 / 3.0 + z * 0.125);
    return (exp(z) * (z - 1.0) + 1.0) / (z * z);
}

// ---------------------------------------------------------------------------
// Kernel B: per (b,h):
//   r[p'] = sum_j lin_w[p',j]
//   v[p'] = sum_j lin_w[p',j]*sk[j] + lin_b[p']
//   M = a r^T + 1 v^T  (a = sq[b,h,:]),  exp(M) = I + U phi(S) W^T,
//   S = [[r.a, r.1],[v.a, v.1]]  (2x2, double)
//   k_new = k + a * y1 + y2,  [y1;y2] = phi(S) * (W^T k)
// One block of 256 threads per (b,h).
// ---------------------------------------------------------------------------
__global__ __launch_bounds__(256) void ka_rank2_expm_kernel(
    const float* __restrict__ k, const float* __restrict__ lin_w,
    const float* __restrict__ lin_b, const float* __restrict__ sq,
    const float* __restrict__ sk, float* __restrict__ out_k)
{
    const int bh = blockIdx.x;            // 0..191
    const int t = threadIdx.x;
    const int lane = t & 63;
    const int wv = t >> 6;

    __shared__ float a_sh[KB_P], sk_sh[KB_P], r_sh[KB_P], v_sh[KB_P];
    __shared__ float t1_sh[4][64], t2_sh[4][64];
    __shared__ double red_sh[4][4];
    __shared__ double G_sh[4];

    a_sh[t]  = sq[bh * KB_P + t];
    sk_sh[t] = sk[bh * KB_P + t];
    __syncthreads();

    // r[t], v[t]: stream this thread's lin_w row (1KB) as float4
    float racc = 0.f, vacc = 0.f;
    const float4* wrow = reinterpret_cast<const float4*>(lin_w + (size_t)t * KB_P);
#pragma unroll 4
    for (int j4 = 0; j4 < KB_P / 4; ++j4) {
        float4 w = wrow[j4];
        const float* skp = &sk_sh[j4 * 4];
        racc += w.x + w.y + w.z + w.w;
        vacc = fmaf(w.x, skp[0], vacc);
        vacc = fmaf(w.y, skp[1], vacc);
        vacc = fmaf(w.z, skp[2], vacc);
        vacc = fmaf(w.w, skp[3], vacc);
    }
    r_sh[t] = racc;
    v_sh[t] = vacc + lin_b[t];
    __syncthreads();

    // S entries: 4 dot products over P=256 in double
    double c0 = (double)r_sh[t] * (double)a_sh[t];
    double c1 = (double)r_sh[t];
    double c2 = (double)v_sh[t] * (double)a_sh[t];
    double c3 = (double)v_sh[t];
#pragma unroll
    for (int off = 32; off; off >>= 1) {
        c0 += __shfl_down(c0, off);
        c1 += __shfl_down(c1, off);
        c2 += __shfl_down(c2, off);
        c3 += __shfl_down(c3, off);
    }
    if (lane == 0) {
        red_sh[wv][0] = c0; red_sh[wv][1] = c1;
        red_sh[wv][2] = c2; red_sh[wv][3] = c3;
    }

    // t1[d] = sum_p r[p]*k[p,d],  t2[d] = sum_p v[p]*k[p,d]  (partial per wave)
    const float* kbh = k + (size_t)bh * KB_P * KB_D;
    float t1 = 0.f, t2 = 0.f;
    for (int p = wv; p < KB_P; p += 4) {
        float kv = kbh[p * KB_D + lane];
        t1 = fmaf(r_sh[p], kv, t1);
        t2 = fmaf(v_sh[p], kv, t2);
    }
    t1_sh[wv][lane] = t1;
    t2_sh[wv][lane] = t2;
    __syncthreads();

    if (t == 0) {
        double s11 = 0, s12 = 0, s21 = 0, s22 = 0;
        for (int w2 = 0; w2 < 4; ++w2) {
            s11 += red_sh[w2][0]; s12 += red_sh[w2][1];
            s21 += red_sh[w2][2]; s22 += red_sh[w2][3];
        }
        const double tr = s11 + s22;
        const double det = s11 * s22 - s12 * s21;
        const double mu = 0.5 * tr;
        const double disc = mu * mu - det;
        double alpha, beta;
        if (disc >= 0.0) {
            const double w = sqrt(disc);
            if (w > 1e-7 * (1.0 + fabs(mu))) {
                const double l1 = mu + w, l2 = mu - w;
                const double p1 = ka_phi(l1), p2 = ka_phi(l2);
                beta = (p1 - p2) / (2.0 * w);
                alpha = p1 - beta * l1;
            } else {
                beta = ka_phip(mu);
                alpha = ka_phi(mu) - beta * mu;
            }
        } else {
            const double w = sqrt(-disc);      // eigenvalues mu +- i*w, w > 0
            const double em = exp(mu);
            const double nre = em * cos(w) - 1.0;
            const double nim = em * sin(w);
            const double den = mu * mu + w * w;
            const double pre = (nre * mu + nim * w) / den;
            const double pim = (nim * mu - nre * w) / den;
            beta = pim / w;
            alpha = pre - beta * mu;
        }
        G_sh[0] = alpha + beta * s11;   // G = alpha*I + beta*S
        G_sh[1] = beta * s12;
        G_sh[2] = beta * s21;
        G_sh[3] = alpha + beta * s22;
    }
    __syncthreads();

    // total t1/t2 for this lane's d, then y = G * t
    const float t1tot = t1_sh[0][lane] + t1_sh[1][lane] + t1_sh[2][lane] + t1_sh[3][lane];
    const float t2tot = t2_sh[0][lane] + t2_sh[1][lane] + t2_sh[2][lane] + t2_sh[3][lane];
    const float G00 = (float)G_sh[0], G01 = (float)G_sh[1];
    const float G10 = (float)G_sh[2], G11v = (float)G_sh[3];
    const float y1 = G00 * t1tot + G01 * t2tot;
    const float y2 = G10 * t1tot + G11v * t2tot;

    float* obh = out_k + (size_t)bh * KB_P * KB_D;
    for (int p = wv; p < KB_P; p += 4) {
        const float kv = kbh[p * KB_D + lane];
        obh[p * KB_D + lane] = kv + a_sh[p] * y1 + y2;
    }
}

// ---------------------------------------------------------------------------
extern "C" void kernel_launch(void* const* d_in, const int* in_sizes, int n_in,
                              void* d_out, int out_size, void* d_ws, size_t ws_size,
                              hipStream_t stream) {
    const float* q          = (const float*)d_in[0];
    const float* k          = (const float*)d_in[1];
    // d_in[2] = scale (unused by forward)
    const float* grid_v     = (const float*)d_in[3];
    const float* bw         = (const float*)d_in[4];
    const float* coef       = (const float*)d_in[5];
    const float* scale_base = (const float*)d_in[6];
    const float* scale_sp   = (const float*)d_in[7];
    const float* lin_w      = (const float*)d_in[8];
    const float* lin_b      = (const float*)d_in[9];

    float* out = (float*)d_out;
    const size_t tensor_elems = (size_t)KB_B * KB_H * KB_P * KB_D;  // 3,145,728

    float* sq = (float*)d_ws;                 // KB_NROWS floats
    float* sk = sq + KB_NROWS;                // KB_NROWS floats

    // Output 0: q passthrough
    hipMemcpyAsync(out, q, tensor_elems * sizeof(float),
                   hipMemcpyDeviceToDevice, stream);

    // sq / sk
    ka_sig_rowsum_kernel<<<2 * KB_NROWS / 4, 256, 0, stream>>>(
        q, k, grid_v, bw, coef, scale_base, scale_sp, sq, sk);

    // rank-2 expm + k_new
    ka_rank2_expm_kernel<<<KB_B * KB_H, 256, 0, stream>>>(
        k, lin_w, lin_b, sq, sk, out + tensor_elems);
}